// Round 1
// 333.481 us; speedup vs baseline: 1.0594x; 1.0594x over previous
//
#include <hip/hip_runtime.h>
#include <hip/hip_bf16.h>

// GAT: N=50000, E=850000, HID=128, HEADS=8, DH=16, LAYERS=2.
// R5: aggregate restructured to one-wave-per-node, zero LDS / zero barriers:
//     4 edge-parity groups x 16 feature-lanes, dwordx4 bf16 gathers, inline
//     weight computation, shfl_xor final reduction. CSR (col,val) packed int2.

typedef __attribute__((ext_vector_type(8))) short short8;   // 8 bf16 = 4 VGPRs
typedef __attribute__((ext_vector_type(4))) float floatx4;

__device__ __forceinline__ unsigned f2u(float f) { return __float_as_uint(f); }
__device__ __forceinline__ float u2f(unsigned u) { return __uint_as_float(u); }
__device__ __forceinline__ unsigned short f2bf_rne(float x) {
    unsigned u = f2u(x);
    unsigned r = (u + 0x7FFF + ((u >> 16) & 1)) >> 16;
    return (unsigned short)r;
}
__device__ __forceinline__ float bf2f(unsigned short b) { return u2f(((unsigned)b) << 16); }

// ---------------- CSR build ----------------

__global__ void hist_kernel(const int* __restrict__ row, int* __restrict__ deg, int E) {
    int e = blockIdx.x * 256 + threadIdx.x;
    if (e < E) atomicAdd(&deg[row[e]], 1);
}

__global__ void blocksum_kernel(const int* __restrict__ deg, int* __restrict__ bsum, int n) {
    __shared__ int sd[512];
    int t = threadIdx.x;
    int idx = blockIdx.x * 512 + t;
    sd[t] = (idx < n) ? deg[idx] : 0;
    __syncthreads();
    for (int off = 256; off; off >>= 1) {
        if (t < off) sd[t] += sd[t + off];
        __syncthreads();
    }
    if (t == 0) bsum[blockIdx.x] = sd[0];
}

__global__ void scanbsum_kernel(const int* __restrict__ bsum, int* __restrict__ boff,
                                int nb, int* __restrict__ rowptr, int n) {
    __shared__ int sd[128];
    int t = threadIdx.x;
    int v = (t < nb) ? bsum[t] : 0;
    sd[t] = v;
    __syncthreads();
    for (int off = 1; off < 128; off <<= 1) {
        int add = (t >= off) ? sd[t - off] : 0;
        __syncthreads();
        sd[t] += add;
        __syncthreads();
    }
    if (t < nb) boff[t] = sd[t] - v;
    if (t == nb - 1) rowptr[n] = sd[t];
}

__global__ void scanfinal_kernel(const int* __restrict__ deg, const int* __restrict__ boff,
                                 int* __restrict__ rowptr, int* __restrict__ cursor, int n) {
    __shared__ int sd[512];
    int t = threadIdx.x;
    int idx = blockIdx.x * 512 + t;
    int v = (idx < n) ? deg[idx] : 0;
    sd[t] = v;
    __syncthreads();
    for (int off = 1; off < 512; off <<= 1) {
        int add = (t >= off) ? sd[t - off] : 0;
        __syncthreads();
        sd[t] += add;
        __syncthreads();
    }
    if (idx < n) {
        int excl = sd[t] - v + boff[blockIdx.x];
        rowptr[idx] = excl;
        cursor[idx] = excl;
    }
}

__global__ void scatter_kernel(const int* __restrict__ row, const int* __restrict__ colv,
                               const float* __restrict__ ev, int* __restrict__ cursor,
                               int2* __restrict__ csr_cv, int E) {
    int e = blockIdx.x * 256 + threadIdx.x;
    if (e < E) {
        int r = row[e];
        int slot = atomicAdd(&cursor[r], 1);
        csr_cv[slot] = make_int2(colv[e], __float_as_int(ev[e]));
    }
}

// ---------------- W pack: fp32 -> split-bf16 B-fragment layout ----------------

__global__ void pack_kernel(const float* __restrict__ encW, const float* __restrict__ Wstack,
                            short8* __restrict__ Wh, short8* __restrict__ Wl) {
    int idx = blockIdx.x * 256 + threadIdx.x;
    if (idx >= 3 * 2048) return;
    int mat = idx >> 11;
    int r = idx & 2047;
    int lane = r & 63;
    int tile = r >> 6;            // ct*4 + kt
    int ct = tile >> 2, kt = tile & 3;
    int ncol = ct * 16 + (lane & 15);
    int k0 = kt * 32 + ((lane >> 4) * 8);
    short8 hv, lv;
#pragma unroll
    for (int j = 0; j < 8; ++j) {
        int k = k0 + j;
        float w = (mat == 0)
            ? encW[k * 128 + ncol]
            : Wstack[(mat - 1) * 16384 + (ncol >> 4) * 2048 + k * 16 + (ncol & 15)];
        unsigned u = f2u(w);
        hv[j] = (short)(u >> 16);
        float hf = u2f(u & 0xFFFF0000u);
        float l = w - hf;
        lv[j] = (short)(f2u(l) >> 16);
    }
    Wh[idx] = hv;
    Wl[idx] = lv;
}

// ---------------- MFMA GEMM ----------------
// flags: bit0 = add bias, bit1 = alpha epilogue, bit2 = store C as bf16.

__global__ __launch_bounds__(256) void
gemm_mfma(const float* __restrict__ A, const short8* __restrict__ Bh,
          const short8* __restrict__ Bl, const float* __restrict__ bias,
          const float* __restrict__ avec, float* __restrict__ Cf,
          unsigned short* __restrict__ Cbf,
          float* __restrict__ asrc, float* __restrict__ adst, int n, int flags) {
    int wave = threadIdx.x >> 6;
    int lane = threadIdx.x & 63;
    int q = lane >> 4;
    int col = lane & 15;
    int n0w = blockIdx.x * 64 + wave * 16;

    int arow = min(n0w + col, n - 1);
    const float* Arow = A + (size_t)arow * 128;
    int kb = q * 8;
    short8 Ah[4], Al[4];
#pragma unroll
    for (int kt = 0; kt < 4; ++kt) {
        float4 f0 = *(const float4*)(Arow + kt * 32 + kb);
        float4 f1 = *(const float4*)(Arow + kt * 32 + kb + 4);
        float fv[8] = {f0.x, f0.y, f0.z, f0.w, f1.x, f1.y, f1.z, f1.w};
#pragma unroll
        for (int j = 0; j < 8; ++j) {
            unsigned u = f2u(fv[j]);
            Ah[kt][j] = (short)(u >> 16);
            float hf = u2f(u & 0xFFFF0000u);
            float l = fv[j] - hf;
            Al[kt][j] = (short)(f2u(l) >> 16);
        }
    }

    int nbase = n0w + q * 4;
#pragma unroll
    for (int ct = 0; ct < 8; ++ct) {
        short8 bh[4], bl[4];
#pragma unroll
        for (int kt = 0; kt < 4; ++kt) {
            bh[kt] = Bh[(ct * 4 + kt) * 64 + lane];
            bl[kt] = Bl[(ct * 4 + kt) * 64 + lane];
        }
        float bv = (flags & 1) ? bias[ct * 16 + col] : 0.f;
        floatx4 acc = {bv, bv, bv, bv};
#pragma unroll
        for (int kt = 0; kt < 4; ++kt) {
            acc = __builtin_amdgcn_mfma_f32_16x16x32_bf16(Ah[kt], bh[kt], acc, 0, 0, 0);
            acc = __builtin_amdgcn_mfma_f32_16x16x32_bf16(Al[kt], bh[kt], acc, 0, 0, 0);
            acc = __builtin_amdgcn_mfma_f32_16x16x32_bf16(Ah[kt], bl[kt], acc, 0, 0, 0);
        }
#pragma unroll
        for (int reg = 0; reg < 4; ++reg) {
            int node = nbase + reg;
            if (node < n) {
                if (flags & 4) Cbf[(size_t)node * 128 + ct * 16 + col] = f2bf_rne(acc[reg]);
                else           Cf[(size_t)node * 128 + ct * 16 + col] = acc[reg];
            }
        }
        if (flags & 2) {
            float a_s = avec[ct * 32 + col];
            float a_d = avec[ct * 32 + 16 + col];
#pragma unroll
            for (int reg = 0; reg < 4; ++reg) {
                float ps = acc[reg] * a_s;
                float pd = acc[reg] * a_d;
#pragma unroll
                for (int off = 8; off; off >>= 1) {
                    ps += __shfl_down(ps, off, 16);
                    pd += __shfl_down(pd, off, 16);
                }
                int node = nbase + reg;
                if (col == 0 && node < n) {
                    asrc[node * 8 + ct] = ps;
                    adst[node * 8 + ct] = pd;
                }
            }
        }
    }
}

// ---------------- aggregate: one wave per node, no LDS, no barriers ----------------
// Wave = 64 lanes = 4 edge-parity groups (grp = lane>>4) x 16 feature-lanes
// (l4 = lane&15). Lane owns features 8*l4 .. 8*l4+7 (all in head l4>>1).
// Group g processes edges j = s+g, s+g+4, ...; weight computed inline per lane
// (redundant exp across the 2 lanes/head/group is cheap). Final: shfl_xor
// reduction across groups, lanes of group 0 write the 512B output row.

__global__ __launch_bounds__(256) void
aggregate_kernel(const int* __restrict__ rowptr, const int2* __restrict__ cv,
                 const unsigned short* __restrict__ hbf,
                 const float* __restrict__ asrc, const float* __restrict__ adst,
                 const float* __restrict__ resid, float* __restrict__ out,
                 int mode, int n) {
    int wid = (blockIdx.x * 256 + threadIdx.x) >> 6;   // wave id = node
    if (wid >= n) return;                              // wave-uniform
    int lane = threadIdx.x & 63;
    int grp = lane >> 4;        // edge parity group 0..3
    int l4 = lane & 15;         // feature lane: features 8*l4 .. 8*l4+7
    int h = l4 >> 1;            // head of this lane's features

    int s = rowptr[wid];
    int e = rowptr[wid + 1];
    float as_w = asrc[wid * 8 + h];

    float a0 = 0.f, a1 = 0.f, a2 = 0.f, a3 = 0.f;
    float a4 = 0.f, a5 = 0.f, a6 = 0.f, a7 = 0.f;
    float ws = 0.f;

#pragma unroll 2
    for (int j = s + grp; j < e; j += 4) {
        int2 cvj = cv[j];
        int c = cvj.x;
        float v = __int_as_float(cvj.y);
        float lg = v * (as_w + adst[c * 8 + h]);
        float lr = fmaxf(lg, 0.2f * lg);     // leaky_relu(0.2)
        float w = __expf(lr);
        uint4 hv = *(const uint4*)(hbf + (size_t)c * 128 + l4 * 8);
        a0 += w * u2f(hv.x << 16);
        a1 += w * u2f(hv.x & 0xFFFF0000u);
        a2 += w * u2f(hv.y << 16);
        a3 += w * u2f(hv.y & 0xFFFF0000u);
        a4 += w * u2f(hv.z << 16);
        a5 += w * u2f(hv.z & 0xFFFF0000u);
        a6 += w * u2f(hv.w << 16);
        a7 += w * u2f(hv.w & 0xFFFF0000u);
        ws += w;
    }

#define RED4(x) x += __shfl_xor(x, 16); x += __shfl_xor(x, 32);
    RED4(a0) RED4(a1) RED4(a2) RED4(a3)
    RED4(a4) RED4(a5) RED4(a6) RED4(a7)
    RED4(ws)
#undef RED4

    if (grp == 0) {
        float inv = 1.0f / ws;   // self-loop guarantees ws > 0
        float o[8] = {a0 * inv, a1 * inv, a2 * inv, a3 * inv,
                      a4 * inv, a5 * inv, a6 * inv, a7 * inv};
        size_t base = (size_t)wid * 128 + l4 * 8;
        if (mode == 0) {
#pragma unroll
            for (int k = 0; k < 8; ++k) o[k] = o[k] > 0.f ? o[k] : expm1f(o[k]);
        } else {
            float4 r0 = *(const float4*)(resid + base);
            float4 r1 = *(const float4*)(resid + base + 4);
            o[0] += r0.x; o[1] += r0.y; o[2] += r0.z; o[3] += r0.w;
            o[4] += r1.x; o[5] += r1.y; o[6] += r1.z; o[7] += r1.w;
        }
        float4 w0 = {o[0], o[1], o[2], o[3]};
        float4 w1 = {o[4], o[5], o[6], o[7]};
        *(float4*)(out + base) = w0;
        *(float4*)(out + base + 4) = w1;
    }
}

// ---------------- launch ----------------

extern "C" void kernel_launch(void* const* d_in, const int* in_sizes, int n_in,
                              void* d_out, int out_size, void* d_ws, size_t ws_size,
                              hipStream_t stream) {
    const int N = in_sizes[0] / 128;
    const int E = in_sizes[2];

    const float* x      = (const float*)d_in[0];
    const int*   eidx   = (const int*)d_in[1];
    const float* ev     = (const float*)d_in[2];
    const float* encW   = (const float*)d_in[3];
    const float* encb   = (const float*)d_in[4];
    const float* Wstack = (const float*)d_in[5];
    const float* astack = (const float*)d_in[6];
    float* out = (float*)d_out;

    const int* row = eidx;
    const int* colv = eidx + E;

    char* p = (char*)d_ws;
    float* xc   = (float*)p; p += (size_t)N * 128 * 4;
    float* xcB  = (float*)p; p += (size_t)N * 128 * 4;
    unsigned short* hbf = (unsigned short*)p; p += (size_t)N * 128 * 2;
    float* asrc = (float*)p; p += (size_t)N * 8 * 4;
    float* adst = (float*)p; p += (size_t)N * 8 * 4;
    short8* Wh  = (short8*)p; p += 3 * 2048 * 16;
    short8* Wl  = (short8*)p; p += 3 * 2048 * 16;
    int2* csr_cv = (int2*)p; p += (size_t)E * 8;     // 8B-aligned (all prior sizes mult of 16)
    int* rowptr = (int*)p;   p += (size_t)(N + 1) * 4;
    int* cursor = (int*)p;   p += (size_t)N * 4;
    int* deg    = (int*)p;   p += (size_t)N * 4;
    int* bsum   = (int*)p;   p += 128 * 4;
    int* boff   = (int*)p;

    const int NB = (N + 511) / 512;
    const int GB = (N + 63) / 64;
    const int AGG = (N + 3) / 4;   // 4 nodes (waves) per 256-thread block

    // --- CSR build ---
    hipMemsetAsync(deg, 0, (size_t)N * 4, stream);
    hist_kernel<<<(E + 255) / 256, 256, 0, stream>>>(row, deg, E);
    blocksum_kernel<<<NB, 512, 0, stream>>>(deg, bsum, N);
    scanbsum_kernel<<<1, 128, 0, stream>>>(bsum, boff, NB, rowptr, N);
    scanfinal_kernel<<<NB, 512, 0, stream>>>(deg, boff, rowptr, cursor, N);
    scatter_kernel<<<(E + 255) / 256, 256, 0, stream>>>(row, colv, ev, cursor, csr_cv, E);

    // --- pack weights ---
    pack_kernel<<<24, 256, 0, stream>>>(encW, Wstack, Wh, Wl);

    // --- encoder: xc = x @ encW + b (fp32 out) ---
    gemm_mfma<<<GB, 256, 0, stream>>>(x, Wh, Wl, encb, nullptr, xc, nullptr,
                                      nullptr, nullptr, N, 1);

    // --- layer 0: h0 (bf16) + alpha0 ---
    gemm_mfma<<<GB, 256, 0, stream>>>(xc, Wh + 2048, Wl + 2048, nullptr, astack,
                                      nullptr, hbf, asrc, adst, N, 2 | 4);
    aggregate_kernel<<<AGG, 256, 0, stream>>>(rowptr, csr_cv, hbf, asrc, adst,
                                              nullptr, xcB, 0, N);

    // --- layer 1: h1 (bf16) + alpha1 ---
    gemm_mfma<<<GB, 256, 0, stream>>>(xcB, Wh + 4096, Wl + 4096, nullptr, astack + 256,
                                      nullptr, hbf, asrc, adst, N, 2 | 4);
    aggregate_kernel<<<AGG, 256, 0, stream>>>(rowptr, csr_cv, hbf, asrc, adst,
                                              xcB, out, 1, N);
}

// Round 3
// 315.966 us; speedup vs baseline: 1.1182x; 1.0554x over previous
//
#include <hip/hip_runtime.h>
#include <hip/hip_bf16.h>

// GAT: N=50000, E=850000, HID=128, HEADS=8, DH=16, LAYERS=2.
// R6 (resubmit; prior bench failed on container acquisition, not kernel):
//     CSR build rewritten to kill scattered-write amplification:
//     hist captures rank (atomic return), scatter writes only a 4B perm
//     (halves random HBM line traffic), gather pass writes csr_cv coalesced.
//     rank/perm alias the xc buffer (dead before encoder GEMM, stream-ordered).

typedef __attribute__((ext_vector_type(8))) short short8;   // 8 bf16 = 4 VGPRs
typedef __attribute__((ext_vector_type(4))) float floatx4;

__device__ __forceinline__ unsigned f2u(float f) { return __float_as_uint(f); }
__device__ __forceinline__ float u2f(unsigned u) { return __uint_as_float(u); }
__device__ __forceinline__ unsigned short f2bf_rne(float x) {
    unsigned u = f2u(x);
    unsigned r = (u + 0x7FFF + ((u >> 16) & 1)) >> 16;
    return (unsigned short)r;
}
__device__ __forceinline__ float bf2f(unsigned short b) { return u2f(((unsigned)b) << 16); }

// ---------------- CSR build ----------------

__global__ void hist_kernel(const int* __restrict__ row, int* __restrict__ deg,
                            int* __restrict__ rank, int E) {
    int e = blockIdx.x * 256 + threadIdx.x;
    if (e < E) rank[e] = atomicAdd(&deg[row[e]], 1);
}

__global__ void blocksum_kernel(const int* __restrict__ deg, int* __restrict__ bsum, int n) {
    __shared__ int sd[512];
    int t = threadIdx.x;
    int idx = blockIdx.x * 512 + t;
    sd[t] = (idx < n) ? deg[idx] : 0;
    __syncthreads();
    for (int off = 256; off; off >>= 1) {
        if (t < off) sd[t] += sd[t + off];
        __syncthreads();
    }
    if (t == 0) bsum[blockIdx.x] = sd[0];
}

__global__ void scanbsum_kernel(const int* __restrict__ bsum, int* __restrict__ boff,
                                int nb, int* __restrict__ rowptr, int n) {
    __shared__ int sd[128];
    int t = threadIdx.x;
    int v = (t < nb) ? bsum[t] : 0;
    sd[t] = v;
    __syncthreads();
    for (int off = 1; off < 128; off <<= 1) {
        int add = (t >= off) ? sd[t - off] : 0;
        __syncthreads();
        sd[t] += add;
        __syncthreads();
    }
    if (t < nb) boff[t] = sd[t] - v;
    if (t == nb - 1) rowptr[n] = sd[t];
}

__global__ void scanfinal_kernel(const int* __restrict__ deg, const int* __restrict__ boff,
                                 int* __restrict__ rowptr, int n) {
    __shared__ int sd[512];
    int t = threadIdx.x;
    int idx = blockIdx.x * 512 + t;
    int v = (idx < n) ? deg[idx] : 0;
    sd[t] = v;
    __syncthreads();
    for (int off = 1; off < 512; off <<= 1) {
        int add = (t >= off) ? sd[t - off] : 0;
        __syncthreads();
        sd[t] += add;
        __syncthreads();
    }
    if (idx < n) rowptr[idx] = sd[t] - v + boff[blockIdx.x];
}

// slot = rowptr[r] + rank[e]; only scattered write is 4B perm.
__global__ void scatterperm_kernel(const int* __restrict__ row, const int* __restrict__ rank,
                                   const int* __restrict__ rowptr, int* __restrict__ perm,
                                   int E) {
    int e = blockIdx.x * 256 + threadIdx.x;
    if (e < E) perm[rowptr[row[e]] + rank[e]] = e;
}

// coalesced csr_cv fill: scattered READS (L2/L3-resident), coalesced writes.
__global__ void gathercv_kernel(const int* __restrict__ perm, const int* __restrict__ colv,
                                const float* __restrict__ ev, int2* __restrict__ csr_cv,
                                int E) {
    int s = blockIdx.x * 256 + threadIdx.x;
    if (s < E) {
        int e = perm[s];
        csr_cv[s] = make_int2(colv[e], __float_as_int(ev[e]));
    }
}

// ---------------- W pack: fp32 -> split-bf16 B-fragment layout ----------------

__global__ void pack_kernel(const float* __restrict__ encW, const float* __restrict__ Wstack,
                            short8* __restrict__ Wh, short8* __restrict__ Wl) {
    int idx = blockIdx.x * 256 + threadIdx.x;
    if (idx >= 3 * 2048) return;
    int mat = idx >> 11;
    int r = idx & 2047;
    int lane = r & 63;
    int tile = r >> 6;            // ct*4 + kt
    int ct = tile >> 2, kt = tile & 3;
    int ncol = ct * 16 + (lane & 15);
    int k0 = kt * 32 + ((lane >> 4) * 8);
    short8 hv, lv;
#pragma unroll
    for (int j = 0; j < 8; ++j) {
        int k = k0 + j;
        float w = (mat == 0)
            ? encW[k * 128 + ncol]
            : Wstack[(mat - 1) * 16384 + (ncol >> 4) * 2048 + k * 16 + (ncol & 15)];
        unsigned u = f2u(w);
        hv[j] = (short)(u >> 16);
        float hf = u2f(u & 0xFFFF0000u);
        float l = w - hf;
        lv[j] = (short)(f2u(l) >> 16);
    }
    Wh[idx] = hv;
    Wl[idx] = lv;
}

// ---------------- MFMA GEMM ----------------
// flags: bit0 = add bias, bit1 = alpha epilogue, bit2 = store C as bf16.

__global__ __launch_bounds__(256) void
gemm_mfma(const float* __restrict__ A, const short8* __restrict__ Bh,
          const short8* __restrict__ Bl, const float* __restrict__ bias,
          const float* __restrict__ avec, float* __restrict__ Cf,
          unsigned short* __restrict__ Cbf,
          float* __restrict__ asrc, float* __restrict__ adst, int n, int flags) {
    int wave = threadIdx.x >> 6;
    int lane = threadIdx.x & 63;
    int q = lane >> 4;
    int col = lane & 15;
    int n0w = blockIdx.x * 64 + wave * 16;

    int arow = min(n0w + col, n - 1);
    const float* Arow = A + (size_t)arow * 128;
    int kb = q * 8;
    short8 Ah[4], Al[4];
#pragma unroll
    for (int kt = 0; kt < 4; ++kt) {
        float4 f0 = *(const float4*)(Arow + kt * 32 + kb);
        float4 f1 = *(const float4*)(Arow + kt * 32 + kb + 4);
        float fv[8] = {f0.x, f0.y, f0.z, f0.w, f1.x, f1.y, f1.z, f1.w};
#pragma unroll
        for (int j = 0; j < 8; ++j) {
            unsigned u = f2u(fv[j]);
            Ah[kt][j] = (short)(u >> 16);
            float hf = u2f(u & 0xFFFF0000u);
            float l = fv[j] - hf;
            Al[kt][j] = (short)(f2u(l) >> 16);
        }
    }

    int nbase = n0w + q * 4;
#pragma unroll
    for (int ct = 0; ct < 8; ++ct) {
        short8 bh[4], bl[4];
#pragma unroll
        for (int kt = 0; kt < 4; ++kt) {
            bh[kt] = Bh[(ct * 4 + kt) * 64 + lane];
            bl[kt] = Bl[(ct * 4 + kt) * 64 + lane];
        }
        float bv = (flags & 1) ? bias[ct * 16 + col] : 0.f;
        floatx4 acc = {bv, bv, bv, bv};
#pragma unroll
        for (int kt = 0; kt < 4; ++kt) {
            acc = __builtin_amdgcn_mfma_f32_16x16x32_bf16(Ah[kt], bh[kt], acc, 0, 0, 0);
            acc = __builtin_amdgcn_mfma_f32_16x16x32_bf16(Al[kt], bh[kt], acc, 0, 0, 0);
            acc = __builtin_amdgcn_mfma_f32_16x16x32_bf16(Ah[kt], bl[kt], acc, 0, 0, 0);
        }
#pragma unroll
        for (int reg = 0; reg < 4; ++reg) {
            int node = nbase + reg;
            if (node < n) {
                if (flags & 4) Cbf[(size_t)node * 128 + ct * 16 + col] = f2bf_rne(acc[reg]);
                else           Cf[(size_t)node * 128 + ct * 16 + col] = acc[reg];
            }
        }
        if (flags & 2) {
            float a_s = avec[ct * 32 + col];
            float a_d = avec[ct * 32 + 16 + col];
#pragma unroll
            for (int reg = 0; reg < 4; ++reg) {
                float ps = acc[reg] * a_s;
                float pd = acc[reg] * a_d;
#pragma unroll
                for (int off = 8; off; off >>= 1) {
                    ps += __shfl_down(ps, off, 16);
                    pd += __shfl_down(pd, off, 16);
                }
                int node = nbase + reg;
                if (col == 0 && node < n) {
                    asrc[node * 8 + ct] = ps;
                    adst[node * 8 + ct] = pd;
                }
            }
        }
    }
}

// ---------------- aggregate: one wave per node, no LDS, no barriers ----------------
// Wave = 64 lanes = 4 edge-parity groups (grp = lane>>4) x 16 feature-lanes
// (l4 = lane&15). Lane owns features 8*l4 .. 8*l4+7 (all in head l4>>1).
// Group g processes edges j = s+g, s+g+4, ...; weight computed inline per lane
// (redundant exp across the 2 lanes/head/group is cheap). Final: shfl_xor
// reduction across groups, lanes of group 0 write the 512B output row.

__global__ __launch_bounds__(256) void
aggregate_kernel(const int* __restrict__ rowptr, const int2* __restrict__ cv,
                 const unsigned short* __restrict__ hbf,
                 const float* __restrict__ asrc, const float* __restrict__ adst,
                 const float* __restrict__ resid, float* __restrict__ out,
                 int mode, int n) {
    int wid = (blockIdx.x * 256 + threadIdx.x) >> 6;   // wave id = node
    if (wid >= n) return;                              // wave-uniform
    int lane = threadIdx.x & 63;
    int grp = lane >> 4;        // edge parity group 0..3
    int l4 = lane & 15;         // feature lane: features 8*l4 .. 8*l4+7
    int h = l4 >> 1;            // head of this lane's features

    int s = rowptr[wid];
    int e = rowptr[wid + 1];
    float as_w = asrc[wid * 8 + h];

    float a0 = 0.f, a1 = 0.f, a2 = 0.f, a3 = 0.f;
    float a4 = 0.f, a5 = 0.f, a6 = 0.f, a7 = 0.f;
    float ws = 0.f;

#pragma unroll 2
    for (int j = s + grp; j < e; j += 4) {
        int2 cvj = cv[j];
        int c = cvj.x;
        float v = __int_as_float(cvj.y);
        float lg = v * (as_w + adst[c * 8 + h]);
        float lr = fmaxf(lg, 0.2f * lg);     // leaky_relu(0.2)
        float w = __expf(lr);
        uint4 hv = *(const uint4*)(hbf + (size_t)c * 128 + l4 * 8);
        a0 += w * u2f(hv.x << 16);
        a1 += w * u2f(hv.x & 0xFFFF0000u);
        a2 += w * u2f(hv.y << 16);
        a3 += w * u2f(hv.y & 0xFFFF0000u);
        a4 += w * u2f(hv.z << 16);
        a5 += w * u2f(hv.z & 0xFFFF0000u);
        a6 += w * u2f(hv.w << 16);
        a7 += w * u2f(hv.w & 0xFFFF0000u);
        ws += w;
    }

#define RED4(x) x += __shfl_xor(x, 16); x += __shfl_xor(x, 32);
    RED4(a0) RED4(a1) RED4(a2) RED4(a3)
    RED4(a4) RED4(a5) RED4(a6) RED4(a7)
    RED4(ws)
#undef RED4

    if (grp == 0) {
        float inv = 1.0f / ws;   // self-loop guarantees ws > 0
        float o[8] = {a0 * inv, a1 * inv, a2 * inv, a3 * inv,
                      a4 * inv, a5 * inv, a6 * inv, a7 * inv};
        size_t base = (size_t)wid * 128 + l4 * 8;
        if (mode == 0) {
#pragma unroll
            for (int k = 0; k < 8; ++k) o[k] = o[k] > 0.f ? o[k] : expm1f(o[k]);
        } else {
            float4 r0 = *(const float4*)(resid + base);
            float4 r1 = *(const float4*)(resid + base + 4);
            o[0] += r0.x; o[1] += r0.y; o[2] += r0.z; o[3] += r0.w;
            o[4] += r1.x; o[5] += r1.y; o[6] += r1.z; o[7] += r1.w;
        }
        float4 w0 = {o[0], o[1], o[2], o[3]};
        float4 w1 = {o[4], o[5], o[6], o[7]};
        *(float4*)(out + base) = w0;
        *(float4*)(out + base + 4) = w1;
    }
}

// ---------------- launch ----------------

extern "C" void kernel_launch(void* const* d_in, const int* in_sizes, int n_in,
                              void* d_out, int out_size, void* d_ws, size_t ws_size,
                              hipStream_t stream) {
    const int N = in_sizes[0] / 128;
    const int E = in_sizes[2];

    const float* x      = (const float*)d_in[0];
    const int*   eidx   = (const int*)d_in[1];
    const float* ev     = (const float*)d_in[2];
    const float* encW   = (const float*)d_in[3];
    const float* encb   = (const float*)d_in[4];
    const float* Wstack = (const float*)d_in[5];
    const float* astack = (const float*)d_in[6];
    float* out = (float*)d_out;

    const int* row = eidx;
    const int* colv = eidx + E;

    char* p = (char*)d_ws;
    float* xc   = (float*)p; p += (size_t)N * 128 * 4;
    float* xcB  = (float*)p; p += (size_t)N * 128 * 4;
    unsigned short* hbf = (unsigned short*)p; p += (size_t)N * 128 * 2;
    float* asrc = (float*)p; p += (size_t)N * 8 * 4;
    float* adst = (float*)p; p += (size_t)N * 8 * 4;
    short8* Wh  = (short8*)p; p += 3 * 2048 * 16;
    short8* Wl  = (short8*)p; p += 3 * 2048 * 16;
    int2* csr_cv = (int2*)p; p += (size_t)E * 8;     // 8B-aligned (all prior sizes mult of 16)
    int* rowptr = (int*)p;   p += (size_t)(N + 1) * 4;
    int* deg    = (int*)p;   p += (size_t)N * 4;
    int* bsum   = (int*)p;   p += 128 * 4;
    int* boff   = (int*)p;

    // rank/perm alias the xc buffer: both are dead before the encoder GEMM
    // writes xc (stream-ordered, same stream). E*2*4 = 6.8MB << 25.6MB.
    int* rank = (int*)xc;
    int* perm = rank + E;

    const int NB = (N + 511) / 512;
    const int GB = (N + 63) / 64;
    const int AGG = (N + 3) / 4;   // 4 nodes (waves) per 256-thread block
    const int EB = (E + 255) / 256;

    // --- CSR build ---
    hipMemsetAsync(deg, 0, (size_t)N * 4, stream);
    hist_kernel<<<EB, 256, 0, stream>>>(row, deg, rank, E);
    blocksum_kernel<<<NB, 512, 0, stream>>>(deg, bsum, N);
    scanbsum_kernel<<<1, 128, 0, stream>>>(bsum, boff, NB, rowptr, N);
    scanfinal_kernel<<<NB, 512, 0, stream>>>(deg, boff, rowptr, N);
    scatterperm_kernel<<<EB, 256, 0, stream>>>(row, rank, rowptr, perm, E);
    gathercv_kernel<<<EB, 256, 0, stream>>>(perm, colv, ev, csr_cv, E);

    // --- pack weights ---
    pack_kernel<<<24, 256, 0, stream>>>(encW, Wstack, Wh, Wl);

    // --- encoder: xc = x @ encW + b (fp32 out) ---
    gemm_mfma<<<GB, 256, 0, stream>>>(x, Wh, Wl, encb, nullptr, xc, nullptr,
                                      nullptr, nullptr, N, 1);

    // --- layer 0: h0 (bf16) + alpha0 ---
    gemm_mfma<<<GB, 256, 0, stream>>>(xc, Wh + 2048, Wl + 2048, nullptr, astack,
                                      nullptr, hbf, asrc, adst, N, 2 | 4);
    aggregate_kernel<<<AGG, 256, 0, stream>>>(rowptr, csr_cv, hbf, asrc, adst,
                                              nullptr, xcB, 0, N);

    // --- layer 1: h1 (bf16) + alpha1 ---
    gemm_mfma<<<GB, 256, 0, stream>>>(xcB, Wh + 4096, Wl + 4096, nullptr, astack + 256,
                                      nullptr, hbf, asrc, adst, N, 2 | 4);
    aggregate_kernel<<<AGG, 256, 0, stream>>>(rowptr, csr_cv, hbf, asrc, adst,
                                              xcB, out, 1, N);
}

// Round 4
// 312.211 us; speedup vs baseline: 1.1316x; 1.0120x over previous
//
#include <hip/hip_runtime.h>
#include <hip/hip_bf16.h>

// GAT: N=50000, E=850000, HID=128, HEADS=8, DH=16, LAYERS=2.
// R7: aggregate edge loop unrolled x4 (16 h-rows in flight/wave) and
//     accumulation packed into float2 ops (v_pk_fma_f32 path). CSR build,
//     GEMM, pack unchanged from R6 (verified at 316 us).

typedef __attribute__((ext_vector_type(8))) short short8;   // 8 bf16 = 4 VGPRs
typedef __attribute__((ext_vector_type(4))) float floatx4;
typedef __attribute__((ext_vector_type(2))) float floatx2;

__device__ __forceinline__ unsigned f2u(float f) { return __float_as_uint(f); }
__device__ __forceinline__ float u2f(unsigned u) { return __uint_as_float(u); }
__device__ __forceinline__ unsigned short f2bf_rne(float x) {
    unsigned u = f2u(x);
    unsigned r = (u + 0x7FFF + ((u >> 16) & 1)) >> 16;
    return (unsigned short)r;
}
__device__ __forceinline__ float bf2f(unsigned short b) { return u2f(((unsigned)b) << 16); }

// ---------------- CSR build ----------------

__global__ void hist_kernel(const int* __restrict__ row, int* __restrict__ deg,
                            int* __restrict__ rank, int E) {
    int e = blockIdx.x * 256 + threadIdx.x;
    if (e < E) rank[e] = atomicAdd(&deg[row[e]], 1);
}

__global__ void blocksum_kernel(const int* __restrict__ deg, int* __restrict__ bsum, int n) {
    __shared__ int sd[512];
    int t = threadIdx.x;
    int idx = blockIdx.x * 512 + t;
    sd[t] = (idx < n) ? deg[idx] : 0;
    __syncthreads();
    for (int off = 256; off; off >>= 1) {
        if (t < off) sd[t] += sd[t + off];
        __syncthreads();
    }
    if (t == 0) bsum[blockIdx.x] = sd[0];
}

__global__ void scanbsum_kernel(const int* __restrict__ bsum, int* __restrict__ boff,
                                int nb, int* __restrict__ rowptr, int n) {
    __shared__ int sd[128];
    int t = threadIdx.x;
    int v = (t < nb) ? bsum[t] : 0;
    sd[t] = v;
    __syncthreads();
    for (int off = 1; off < 128; off <<= 1) {
        int add = (t >= off) ? sd[t - off] : 0;
        __syncthreads();
        sd[t] += add;
        __syncthreads();
    }
    if (t < nb) boff[t] = sd[t] - v;
    if (t == nb - 1) rowptr[n] = sd[t];
}

__global__ void scanfinal_kernel(const int* __restrict__ deg, const int* __restrict__ boff,
                                 int* __restrict__ rowptr, int n) {
    __shared__ int sd[512];
    int t = threadIdx.x;
    int idx = blockIdx.x * 512 + t;
    int v = (idx < n) ? deg[idx] : 0;
    sd[t] = v;
    __syncthreads();
    for (int off = 1; off < 512; off <<= 1) {
        int add = (t >= off) ? sd[t - off] : 0;
        __syncthreads();
        sd[t] += add;
        __syncthreads();
    }
    if (idx < n) rowptr[idx] = sd[t] - v + boff[blockIdx.x];
}

// slot = rowptr[r] + rank[e]; only scattered write is 4B perm.
__global__ void scatterperm_kernel(const int* __restrict__ row, const int* __restrict__ rank,
                                   const int* __restrict__ rowptr, int* __restrict__ perm,
                                   int E) {
    int e = blockIdx.x * 256 + threadIdx.x;
    if (e < E) perm[rowptr[row[e]] + rank[e]] = e;
}

// coalesced csr_cv fill: scattered READS (L2/L3-resident), coalesced writes.
__global__ void gathercv_kernel(const int* __restrict__ perm, const int* __restrict__ colv,
                                const float* __restrict__ ev, int2* __restrict__ csr_cv,
                                int E) {
    int s = blockIdx.x * 256 + threadIdx.x;
    if (s < E) {
        int e = perm[s];
        csr_cv[s] = make_int2(colv[e], __float_as_int(ev[e]));
    }
}

// ---------------- W pack: fp32 -> split-bf16 B-fragment layout ----------------

__global__ void pack_kernel(const float* __restrict__ encW, const float* __restrict__ Wstack,
                            short8* __restrict__ Wh, short8* __restrict__ Wl) {
    int idx = blockIdx.x * 256 + threadIdx.x;
    if (idx >= 3 * 2048) return;
    int mat = idx >> 11;
    int r = idx & 2047;
    int lane = r & 63;
    int tile = r >> 6;            // ct*4 + kt
    int ct = tile >> 2, kt = tile & 3;
    int ncol = ct * 16 + (lane & 15);
    int k0 = kt * 32 + ((lane >> 4) * 8);
    short8 hv, lv;
#pragma unroll
    for (int j = 0; j < 8; ++j) {
        int k = k0 + j;
        float w = (mat == 0)
            ? encW[k * 128 + ncol]
            : Wstack[(mat - 1) * 16384 + (ncol >> 4) * 2048 + k * 16 + (ncol & 15)];
        unsigned u = f2u(w);
        hv[j] = (short)(u >> 16);
        float hf = u2f(u & 0xFFFF0000u);
        float l = w - hf;
        lv[j] = (short)(f2u(l) >> 16);
    }
    Wh[idx] = hv;
    Wl[idx] = lv;
}

// ---------------- MFMA GEMM ----------------
// flags: bit0 = add bias, bit1 = alpha epilogue, bit2 = store C as bf16.

__global__ __launch_bounds__(256) void
gemm_mfma(const float* __restrict__ A, const short8* __restrict__ Bh,
          const short8* __restrict__ Bl, const float* __restrict__ bias,
          const float* __restrict__ avec, float* __restrict__ Cf,
          unsigned short* __restrict__ Cbf,
          float* __restrict__ asrc, float* __restrict__ adst, int n, int flags) {
    int wave = threadIdx.x >> 6;
    int lane = threadIdx.x & 63;
    int q = lane >> 4;
    int col = lane & 15;
    int n0w = blockIdx.x * 64 + wave * 16;

    int arow = min(n0w + col, n - 1);
    const float* Arow = A + (size_t)arow * 128;
    int kb = q * 8;
    short8 Ah[4], Al[4];
#pragma unroll
    for (int kt = 0; kt < 4; ++kt) {
        float4 f0 = *(const float4*)(Arow + kt * 32 + kb);
        float4 f1 = *(const float4*)(Arow + kt * 32 + kb + 4);
        float fv[8] = {f0.x, f0.y, f0.z, f0.w, f1.x, f1.y, f1.z, f1.w};
#pragma unroll
        for (int j = 0; j < 8; ++j) {
            unsigned u = f2u(fv[j]);
            Ah[kt][j] = (short)(u >> 16);
            float hf = u2f(u & 0xFFFF0000u);
            float l = fv[j] - hf;
            Al[kt][j] = (short)(f2u(l) >> 16);
        }
    }

    int nbase = n0w + q * 4;
#pragma unroll
    for (int ct = 0; ct < 8; ++ct) {
        short8 bh[4], bl[4];
#pragma unroll
        for (int kt = 0; kt < 4; ++kt) {
            bh[kt] = Bh[(ct * 4 + kt) * 64 + lane];
            bl[kt] = Bl[(ct * 4 + kt) * 64 + lane];
        }
        float bv = (flags & 1) ? bias[ct * 16 + col] : 0.f;
        floatx4 acc = {bv, bv, bv, bv};
#pragma unroll
        for (int kt = 0; kt < 4; ++kt) {
            acc = __builtin_amdgcn_mfma_f32_16x16x32_bf16(Ah[kt], bh[kt], acc, 0, 0, 0);
            acc = __builtin_amdgcn_mfma_f32_16x16x32_bf16(Al[kt], bh[kt], acc, 0, 0, 0);
            acc = __builtin_amdgcn_mfma_f32_16x16x32_bf16(Ah[kt], bl[kt], acc, 0, 0, 0);
        }
#pragma unroll
        for (int reg = 0; reg < 4; ++reg) {
            int node = nbase + reg;
            if (node < n) {
                if (flags & 4) Cbf[(size_t)node * 128 + ct * 16 + col] = f2bf_rne(acc[reg]);
                else           Cf[(size_t)node * 128 + ct * 16 + col] = acc[reg];
            }
        }
        if (flags & 2) {
            float a_s = avec[ct * 32 + col];
            float a_d = avec[ct * 32 + 16 + col];
#pragma unroll
            for (int reg = 0; reg < 4; ++reg) {
                float ps = acc[reg] * a_s;
                float pd = acc[reg] * a_d;
#pragma unroll
                for (int off = 8; off; off >>= 1) {
                    ps += __shfl_down(ps, off, 16);
                    pd += __shfl_down(pd, off, 16);
                }
                int node = nbase + reg;
                if (col == 0 && node < n) {
                    asrc[node * 8 + ct] = ps;
                    adst[node * 8 + ct] = pd;
                }
            }
        }
    }
}

// ---------------- aggregate: one wave per node, no LDS, no barriers ----------------
// Wave = 64 lanes = 4 edge-parity groups (grp = lane>>4) x 16 feature-lanes
// (l4 = lane&15). Lane owns features 8*l4 .. 8*l4+7 (all in head l4>>1).
// Group g processes edges j = s+g, s+g+4, ...; unroll 4 => 16 h-rows in
// flight per wave. Accumulators are float2 pairs so the bf16 unpack feeds
// v_pk_fma_f32 (2 FMA/inst). Final: shfl_xor reduction across groups.

__global__ __launch_bounds__(256) void
aggregate_kernel(const int* __restrict__ rowptr, const int2* __restrict__ cv,
                 const unsigned short* __restrict__ hbf,
                 const float* __restrict__ asrc, const float* __restrict__ adst,
                 const float* __restrict__ resid, float* __restrict__ out,
                 int mode, int n) {
    int wid = (blockIdx.x * 256 + threadIdx.x) >> 6;   // wave id = node
    if (wid >= n) return;                              // wave-uniform
    int lane = threadIdx.x & 63;
    int grp = lane >> 4;        // edge parity group 0..3
    int l4 = lane & 15;         // feature lane: features 8*l4 .. 8*l4+7
    int h = l4 >> 1;            // head of this lane's features

    int s = rowptr[wid];
    int e = rowptr[wid + 1];
    float as_w = asrc[wid * 8 + h];

    floatx2 acc0 = {0.f, 0.f}, acc1 = {0.f, 0.f};
    floatx2 acc2 = {0.f, 0.f}, acc3 = {0.f, 0.f};
    float ws = 0.f;

#pragma unroll 4
    for (int j = s + grp; j < e; j += 4) {
        int2 cvj = cv[j];
        int c = cvj.x;
        float v = __int_as_float(cvj.y);
        float lg = v * (as_w + adst[c * 8 + h]);
        float lr = fmaxf(lg, 0.2f * lg);     // leaky_relu(0.2)
        float w = __expf(lr);
        uint4 hv = *(const uint4*)(hbf + (size_t)c * 128 + l4 * 8);
        floatx2 w2 = {w, w};
        floatx2 p0 = {u2f(hv.x << 16), u2f(hv.x & 0xFFFF0000u)};
        floatx2 p1 = {u2f(hv.y << 16), u2f(hv.y & 0xFFFF0000u)};
        floatx2 p2 = {u2f(hv.z << 16), u2f(hv.z & 0xFFFF0000u)};
        floatx2 p3 = {u2f(hv.w << 16), u2f(hv.w & 0xFFFF0000u)};
        acc0 += w2 * p0;
        acc1 += w2 * p1;
        acc2 += w2 * p2;
        acc3 += w2 * p3;
        ws += w;
    }

    float a0 = acc0.x, a1 = acc0.y, a2 = acc1.x, a3 = acc1.y;
    float a4 = acc2.x, a5 = acc2.y, a6 = acc3.x, a7 = acc3.y;

#define RED4(x) x += __shfl_xor(x, 16); x += __shfl_xor(x, 32);
    RED4(a0) RED4(a1) RED4(a2) RED4(a3)
    RED4(a4) RED4(a5) RED4(a6) RED4(a7)
    RED4(ws)
#undef RED4

    if (grp == 0) {
        float inv = 1.0f / ws;   // self-loop guarantees ws > 0
        float o[8] = {a0 * inv, a1 * inv, a2 * inv, a3 * inv,
                      a4 * inv, a5 * inv, a6 * inv, a7 * inv};
        size_t base = (size_t)wid * 128 + l4 * 8;
        if (mode == 0) {
#pragma unroll
            for (int k = 0; k < 8; ++k) o[k] = o[k] > 0.f ? o[k] : expm1f(o[k]);
        } else {
            float4 r0 = *(const float4*)(resid + base);
            float4 r1 = *(const float4*)(resid + base + 4);
            o[0] += r0.x; o[1] += r0.y; o[2] += r0.z; o[3] += r0.w;
            o[4] += r1.x; o[5] += r1.y; o[6] += r1.z; o[7] += r1.w;
        }
        float4 w0 = {o[0], o[1], o[2], o[3]};
        float4 w1 = {o[4], o[5], o[6], o[7]};
        *(float4*)(out + base) = w0;
        *(float4*)(out + base + 4) = w1;
    }
}

// ---------------- launch ----------------

extern "C" void kernel_launch(void* const* d_in, const int* in_sizes, int n_in,
                              void* d_out, int out_size, void* d_ws, size_t ws_size,
                              hipStream_t stream) {
    const int N = in_sizes[0] / 128;
    const int E = in_sizes[2];

    const float* x      = (const float*)d_in[0];
    const int*   eidx   = (const int*)d_in[1];
    const float* ev     = (const float*)d_in[2];
    const float* encW   = (const float*)d_in[3];
    const float* encb   = (const float*)d_in[4];
    const float* Wstack = (const float*)d_in[5];
    const float* astack = (const float*)d_in[6];
    float* out = (float*)d_out;

    const int* row = eidx;
    const int* colv = eidx + E;

    char* p = (char*)d_ws;
    float* xc   = (float*)p; p += (size_t)N * 128 * 4;
    float* xcB  = (float*)p; p += (size_t)N * 128 * 4;
    unsigned short* hbf = (unsigned short*)p; p += (size_t)N * 128 * 2;
    float* asrc = (float*)p; p += (size_t)N * 8 * 4;
    float* adst = (float*)p; p += (size_t)N * 8 * 4;
    short8* Wh  = (short8*)p; p += 3 * 2048 * 16;
    short8* Wl  = (short8*)p; p += 3 * 2048 * 16;
    int2* csr_cv = (int2*)p; p += (size_t)E * 8;     // 8B-aligned (all prior sizes mult of 16)
    int* rowptr = (int*)p;   p += (size_t)(N + 1) * 4;
    int* deg    = (int*)p;   p += (size_t)N * 4;
    int* bsum   = (int*)p;   p += 128 * 4;
    int* boff   = (int*)p;

    // rank/perm alias the xc buffer: both are dead before the encoder GEMM
    // writes xc (stream-ordered, same stream). E*2*4 = 6.8MB << 25.6MB.
    int* rank = (int*)xc;
    int* perm = rank + E;

    const int NB = (N + 511) / 512;
    const int GB = (N + 63) / 64;
    const int AGG = (N + 3) / 4;   // 4 nodes (waves) per 256-thread block
    const int EB = (E + 255) / 256;

    // --- CSR build ---
    hipMemsetAsync(deg, 0, (size_t)N * 4, stream);
    hist_kernel<<<EB, 256, 0, stream>>>(row, deg, rank, E);
    blocksum_kernel<<<NB, 512, 0, stream>>>(deg, bsum, N);
    scanbsum_kernel<<<1, 128, 0, stream>>>(bsum, boff, NB, rowptr, N);
    scanfinal_kernel<<<NB, 512, 0, stream>>>(deg, boff, rowptr, N);
    scatterperm_kernel<<<EB, 256, 0, stream>>>(row, rank, rowptr, perm, E);
    gathercv_kernel<<<EB, 256, 0, stream>>>(perm, colv, ev, csr_cv, E);

    // --- pack weights ---
    pack_kernel<<<24, 256, 0, stream>>>(encW, Wstack, Wh, Wl);

    // --- encoder: xc = x @ encW + b (fp32 out) ---
    gemm_mfma<<<GB, 256, 0, stream>>>(x, Wh, Wl, encb, nullptr, xc, nullptr,
                                      nullptr, nullptr, N, 1);

    // --- layer 0: h0 (bf16) + alpha0 ---
    gemm_mfma<<<GB, 256, 0, stream>>>(xc, Wh + 2048, Wl + 2048, nullptr, astack,
                                      nullptr, hbf, asrc, adst, N, 2 | 4);
    aggregate_kernel<<<AGG, 256, 0, stream>>>(rowptr, csr_cv, hbf, asrc, adst,
                                              nullptr, xcB, 0, N);

    // --- layer 1: h1 (bf16) + alpha1 ---
    gemm_mfma<<<GB, 256, 0, stream>>>(xcB, Wh + 4096, Wl + 4096, nullptr, astack + 256,
                                      nullptr, hbf, asrc, adst, N, 2 | 4);
    aggregate_kernel<<<AGG, 256, 0, stream>>>(rowptr, csr_cv, hbf, asrc, adst,
                                              xcB, out, 1, N);
}